// Round 14
// baseline (3348.643 us; speedup 1.0000x reference)
//
#include <hip/hip_runtime.h>

typedef unsigned short u16;
typedef unsigned int u32;
typedef __attribute__((ext_vector_type(8))) short bf16x8;
typedef __attribute__((ext_vector_type(4))) float f32x4;

__device__ __forceinline__ float b2f(u16 h) {
  union { float f; unsigned u; } v; v.u = ((unsigned)h) << 16; return v.f;
}
__device__ __forceinline__ u16 f2b(float f) {
  union { float f; unsigned u; } v; v.f = f;
  unsigned r = v.u + 0x7fffu + ((v.u >> 16) & 1u);
  return (u16)(r >> 16);
}
__device__ __forceinline__ float hsig(float z) {
  return fminf(fmaxf(z * 0.16666667f + 0.5f, 0.f), 1.f);
}
__device__ __forceinline__ float ldf(const void* p, int i, int flag) {
  return flag ? b2f(((const u16*)p)[i]) : ((const float*)p)[i];
}
// 16B-per-lane DMA: global (per-lane addr) -> LDS (wave-uniform base + lane*16)
__device__ __forceinline__ void glds16(const void* g, void* l) {
  __builtin_amdgcn_global_load_lds(
      (const __attribute__((address_space(1))) void*)g,
      (__attribute__((address_space(3))) void*)(u32)(size_t)l, 16, 0, 0);
}

__global__ void detect_dtype(const void* x, int* dflag) {
  __shared__ int cnt;
  if (threadIdx.x == 0) cnt = 0;
  __syncthreads();
  const u32* w = (const u32*)x;
  int c = 0;
  for (int i = threadIdx.x; i < 512; i += 256) {
    u32 e = (w[i] >> 7) & 0xFFu;
    if (e >= 100 && e < 130) c++;
  }
  atomicAdd(&cnt, c);
  __syncthreads();
  if (threadIdx.x == 0) *dflag = (cnt >= 256) ? 1 : 0;
}

__global__ void canon_x(const void* src, u16* dst, const int* dflag, int n) {
  int i = blockIdx.x * 256 + threadIdx.x;
  if (i >= n) return;
  int fl = *dflag;
  float v = ldf(src, i, fl);
  u16 hi = f2b(v);
  dst[i] = hi;
  dst[i + n] = f2b(v - b2f(hi));
}

// ---------------------------------------------------------------------------
// ConvLSTM step body. Implicit-GEMM MFMA 16x16x32 bf16; hi/lo bf16 pairs,
// single-pass (hi & lo co-staged; weights loaded once per tap, 2x MFMA).
// Staging of 32-ch tensors is global_load_lds DMA (16B/lane): each lane
// computes which (pixel, chunk) its LDS slot holds under the XOR swizzle
// (slot = chunk ^ px ^ px>>1) and fetches it; OOB halo lanes read a zeroed
// global page. No VGPR round-trip -> deep DMA queue (round-13 diagnosis:
// latency-limited streaming at 13% HBM BW).
// ---------------------------------------------------------------------------
template<int KS, int MODE, int H, int W, int MROWS>
__device__ __forceinline__
void step_body(int bxi, int b, char* dsm, const u16* __restrict__ zp,
               const u16* __restrict__ src, int aBStride, size_t sPL,
               const u16* __restrict__ wA, const u16* __restrict__ wU,
               const u16* __restrict__ hin, size_t hPL, u16* __restrict__ hout,
               float* __restrict__ cbuf, const void* __restrict__ bias,
               const void* __restrict__ bng, const void* __restrict__ bnb,
               const void* __restrict__ bnm, const void* __restrict__ bnv,
               u16* __restrict__ pooled, size_t pPL, float* __restrict__ gap,
               const int* __restrict__ dflag)
{
  constexpr int PAD = KS / 2;
  constexpr int TW = 8 + 2 * PAD;
  constexpr int TH = MROWS + 2 * PAD;
  constexpr int KK = KS * KS;
  constexpr int KT = (MODE == 0) ? (KK + 1) : (2 * KK);
  constexpr int MT = MROWS / 4;
  constexpr int NPX = TH * TW;
  constexpr int CALLS = (NPX * 32 + 511) / 512;  // 1KB DMA calls per buffer
  constexpr int BUFP = CALLS * 512;              // padded elems per buffer
  constexpr int ASZ0 = (NPX + 15) & ~15;

  u16* sH0 = (u16*)dsm;
  u16* sH1 = sH0 + BUFP;
  u16* sA0 = sH1 + BUFP;
  u16* sA1 = sA0 + ((MODE == 0) ? ASZ0 : BUFP);
  float* sgap = (float*)(sA1 + ((MODE == 0) ? ASZ0 : BUFP));

  const int tid = threadIdx.x;
  constexpr int TXT = W / 8;
  const int bx0 = (bxi % TXT) * 8;
  const int gy0 = (bxi / TXT) * MROWS;

  const int w = tid >> 6, lane = tid & 63;
  const int j = w & 1, R0 = (w >> 1) * (MROWS / 2);
  const int q = lane >> 4, col = lane & 15;
  const int my = (lane >> 3) & 1, mx = lane & 7;

  if (MODE == 2 && tid < 32) sgap[tid] = 0.f;

  // DMA-stage a 32-ch tensor plane into the swizzled LDS buffer
  auto stageC = [&](const u16* gsrc, u16* dst) {
    for (int k = w; k < CALLS; k += 4) {
      int idx = k * 512 + lane * 8;
      int px = idx >> 5;
      int slot = (idx >> 3) & 3;
      int c = (slot ^ px ^ (px >> 1)) & 3;
      int sy = px / TW, sx = px - sy * TW;
      int gy = gy0 + sy - PAD, gx = bx0 + sx - PAD;
      const u16* g = zp;
      if (px < NPX && gy >= 0 && gy < H && gx >= 0 && gx < W)
        g = gsrc + (((size_t)(b * H + gy) * W + gx) << 5) + c * 8;
      glds16(g, dst + (size_t)k * 512);
    }
  };
  auto stageX = [&](int pl, u16* dst) {   // MODE0 single-channel x (small)
    const u16* asrc = src + (size_t)pl * sPL;
    for (int i = tid; i < NPX; i += 256) {
      int sy = i / TW, sx = i - sy * TW;
      int gy = gy0 + sy - PAD, gx = bx0 + sx - PAD;
      u16 v = 0;
      if (gy >= 0 && gy < H && gx >= 0 && gx < W)
        v = asrc[(size_t)b * aBStride + gy * W + gx];
      dst[i] = v;
    }
  };

  const int wfoff = lane * 8;
  auto loadW = [&](int kt, bf16x8* dst) {
    const u16* wsrc;
    if (MODE == 0) wsrc = (kt == 0) ? wA : (wU + (kt - 1) * 4096);
    else           wsrc = (kt < KK) ? (wA + kt * 4096) : (wU + (kt - KK) * 4096);
#pragma unroll
    for (int g = 0; g < 4; g++)
      dst[g] = *(const bf16x8*)(wsrc + ((j + 2 * g) * 64) * 8 + wfoff);
  };

  f32x4 acc[MT][4] = {};
  int pxb[MT];
#pragma unroll
  for (int mt = 0; mt < MT; mt++)
    pxb[mt] = (R0 + 2 * mt + my) * TW + mx;

  stageC(hin, sH0);
  stageC(hin + hPL, sH1);
  if (MODE == 0) { stageX(0, sA0); stageX(1, sA1); }
  else           { stageC(src, sA0); stageC(src + sPL, sA1); }
  __syncthreads();

  bf16x8 bw[4];
  loadW(0, bw);
#pragma unroll 2
  for (int kt = 0; kt < KT; ++kt) {
    bf16x8 nxt[4];
    if (kt + 1 < KT) loadW(kt + 1, nxt);
    bf16x8 ah[MT], al[MT];
    if (MODE == 0 && kt == 0) {
#pragma unroll
      for (int mt = 0; mt < MT; mt++) {
        union { bf16x8 v; u16 e[8]; } uh, ul;
#pragma unroll
        for (int jj = 0; jj < 8; jj++) {
          int k = q * 8 + jj;
          u16 vh = 0, vl = 0;
          if (k < KK) {
            int kh = k / KS, kw = k - kh * KS;
            int o = (R0 + 2 * mt + my + kh) * TW + (mx + kw);
            vh = sA0[o]; vl = sA1[o];
          }
          uh.e[jj] = vh; ul.e[jj] = vl;
        }
        ah[mt] = uh.v; al[mt] = ul.v;
      }
    } else {
      int tap; const u16 *s0, *s1;
      if (MODE == 0)    { tap = kt - 1;  s0 = sH0; s1 = sH1; }
      else if (kt < KK) { tap = kt;      s0 = sA0; s1 = sA1; }
      else              { tap = kt - KK; s0 = sH0; s1 = sH1; }
      const int koff = (tap / KS) * TW + (tap - (tap / KS) * KS);
#pragma unroll
      for (int mt = 0; mt < MT; mt++) {
        const int px = pxb[mt] + koff;
        const int ad = (px << 5) + (((q ^ px ^ (px >> 1)) & 3) << 3);
        ah[mt] = *(const bf16x8*)(s0 + ad);
        al[mt] = *(const bf16x8*)(s1 + ad);
      }
    }
#pragma unroll
    for (int mt = 0; mt < MT; mt++)
#pragma unroll
      for (int g = 0; g < 4; g++)
        acc[mt][g] = __builtin_amdgcn_mfma_f32_16x16x32_bf16(ah[mt], bw[g], acc[mt][g], 0, 0, 0);
#pragma unroll
    for (int mt = 0; mt < MT; mt++)
#pragma unroll
      for (int g = 0; g < 4; g++)
        acc[mt][g] = __builtin_amdgcn_mfma_f32_16x16x32_bf16(al[mt], bw[g], acc[mt][g], 0, 0, 0);
#pragma unroll
    for (int g = 0; g < 4; g++) bw[g] = nxt[g];
  }

  // ---- epilogue: gates, state update, BN+pool / GAP ----
  const int fl = *dflag;
  const int f = j * 16 + col;
  const float bi  = ldf(bias, f, fl);
  const float bff = ldf(bias, 32 + f, fl);
  const float bg  = ldf(bias, 64 + f, fl);
  const float bo  = ldf(bias, 96 + f, fl);
  float sc = 0.f, sh = 0.f;
  if (MODE < 2) {
    sc = ldf(bng, f, fl) * rsqrtf(ldf(bnv, f, fl) + 1e-3f);
    sh = ldf(bnb, f, fl) - ldf(bnm, f, fl) * sc;
  }
  const int oy = q >> 1;
  const int ox = (q & 1) * 4;
  float gsum = 0.f;
#pragma unroll
  for (int mt = 0; mt < MT; mt++) {
    const int y = gy0 + R0 + 2 * mt + oy;
    const size_t base = (((size_t)(b * H + y) * W + (bx0 + ox)) << 5) + f;
    float bnp[4];
#pragma unroll
    for (int r = 0; r < 4; r++) {
      float zi = acc[mt][0][r] + bi;
      float zf = acc[mt][1][r] + bff;
      float zg = acc[mt][2][r] + bg;
      float zo = acc[mt][3][r] + bo;
      float ig = hsig(zi), fg = hsig(zf), og = hsig(zo);
      float gg = fmaxf(zg, 0.f);
      size_t idx = base + ((size_t)r << 5);
      float cold = cbuf[idx];
      float cn = fg * cold + ig * gg;
      cbuf[idx] = cn;
      float hn = og * fmaxf(cn, 0.f);
      u16 hhi = f2b(hn);
      hout[idx] = hhi;
      hout[idx + hPL] = f2b(hn - b2f(hhi));
      if (MODE < 2) bnp[r] = hn * sc + sh; else gsum += hn;
    }
    if (MODE < 2) {
      float p0 = fmaxf(bnp[0], bnp[1]);
      float p1 = fmaxf(bnp[2], bnp[3]);
      p0 = fmaxf(p0, __shfl_xor(p0, 32));
      p1 = fmaxf(p1, __shfl_xor(p1, 32));
      if (q < 2) {
        const int py = (gy0 + R0 + 2 * mt) >> 1;
        const int px = (bx0 >> 1) + (q & 1) * 2;
        size_t pb = (((size_t)(b * (H / 2) + py) * (W / 2) + px) << 5) + f;
        u16 phi = f2b(p0);
        pooled[pb] = phi;
        pooled[pb + pPL] = f2b(p0 - b2f(phi));
        u16 qhi = f2b(p1);
        pooled[pb + 32] = qhi;
        pooled[pb + 32 + pPL] = f2b(p1 - b2f(qhi));
      }
    }
  }
  if (MODE == 2) {
    atomicAdd(&sgap[f], gsum);
    __syncthreads();
    if (tid < 32) atomicAdd(&gap[b * 32 + tid], sgap[tid]);
  }
}

// ---------------------------------------------------------------------------
// Skewed fused dispatch, role-interleaved: 832 = 26 x 32 groups; per group:
// 16 L1(t) + 8 L2(t-1, 8-row) + 2 L3(t-2, 8-row). p1/p2 parity-buffered.
// dyn LDS 36.9 KB -> 4 blocks/CU; all 832 blocks co-resident.
// ---------------------------------------------------------------------------
__global__ __launch_bounds__(256, 4)
void fused_step(int t, const u16* __restrict__ xc, const u16* __restrict__ zp,
                const u16* __restrict__ W1x, const u16* __restrict__ W1u,
                u16* h1a, u16* h1b, float* c1, const void* b1, const void* g1,
                const void* be1, const void* m1, const void* v1, u16* p1,
                const u16* __restrict__ W2k, const u16* __restrict__ W2u,
                u16* h2a, u16* h2b, float* c2, const void* b2, const void* g2,
                const void* be2, const void* m2, const void* v2, u16* p2,
                const u16* __restrict__ W3k, const u16* __restrict__ W3u,
                u16* h3a, u16* h3b, float* c3, const void* b3,
                float* gap, const int* dflag)
{
  extern __shared__ char dsm[];
  const int grp = blockIdx.x / 26;
  const int r   = blockIdx.x % 26;
  if (r < 16) {
    if (t > 15) return;
    const int idx = grp * 16 + r;            // 0..511
    const u16* h1i = (t & 1) ? h1b : h1a; u16* h1o = (t & 1) ? h1a : h1b;
    step_body<5, 0, 64, 64, 16>(idx & 31, idx >> 5, dsm, zp,
        xc + (size_t)t * 4096, 65536, 1048576, W1x, W1u, h1i, 2097152, h1o, c1,
        b1, g1, be1, m1, v1, p1 + (size_t)(t & 1) * 1048576, 524288, nullptr, dflag);
  } else if (r < 24) {
    const int tt = t - 1; if (tt < 0 || tt > 15) return;
    const int idx = grp * 8 + (r - 16);      // 0..255 (16 tiles x 16 b)
    const u16* h2i = (tt & 1) ? h2b : h2a; u16* h2o = (tt & 1) ? h2a : h2b;
    step_body<5, 1, 32, 32, 8>(idx & 15, idx >> 4, dsm, zp,
        p1 + (size_t)(tt & 1) * 1048576, 32768, 524288, W2k, W2u, h2i, 524288, h2o, c2,
        b2, g2, be2, m2, v2, p2 + (size_t)(tt & 1) * 262144, 131072, nullptr, dflag);
  } else {
    const int tt = t - 2; if (tt < 0 || tt > 15) return;
    const int idx = grp * 2 + (r - 24);      // 0..63 (4 tiles x 16 b)
    const u16* h3i = (tt & 1) ? h3b : h3a; u16* h3o = (tt & 1) ? h3a : h3b;
    step_body<3, 2, 16, 16, 8>(idx & 3, idx >> 2, dsm, zp,
        p2 + (size_t)(tt & 1) * 262144, 8192, 131072, W3k, W3u, h3i, 131072, h3o, c3,
        b3, nullptr, nullptr, nullptr, nullptr, nullptr, 0, gap, dflag);
  }
}

__global__ void repack_w(const void* __restrict__ src, u16* __restrict__ dst,
                         int taps, const int* __restrict__ dflag) {
  int i = blockIdx.x * 256 + threadIdx.x;
  if (i >= taps * 512) return;
  int fl = *dflag;
  int l = i & 63, nt = (i >> 6) & 7, tap = i >> 9;
  int q = l >> 4, col = l & 15;
  u16 tmp[8];
#pragma unroll
  for (int j = 0; j < 8; j++)
    tmp[j] = f2b(ldf(src, (tap * 32 + q * 8 + j) * 128 + nt * 16 + col, fl));
#pragma unroll
  for (int j = 0; j < 8; j++) dst[i * 8 + j] = tmp[j];
}
__global__ void repack_x(const void* __restrict__ src, u16* __restrict__ dst,
                         const int* __restrict__ dflag) {
  int i = blockIdx.x * 256 + threadIdx.x;
  if (i >= 512) return;
  int fl = *dflag;
  int l = i & 63, nt = (i >> 6) & 7;
  int q = l >> 4, col = l & 15;
#pragma unroll
  for (int j = 0; j < 8; j++) {
    int k = q * 8 + j;
    dst[i * 8 + j] = (k < 25) ? f2b(ldf(src, k * 128 + nt * 16 + col, fl)) : (u16)0;
  }
}

__global__ void zero_ws(int4* p, int n) {
  int i = blockIdx.x * 256 + threadIdx.x;
  if (i < n) { int4 z; z.x = z.y = z.z = z.w = 0; p[i] = z; }
}
__global__ void fillv(float* out, int n, float v) {
  int i = blockIdx.x * 256 + threadIdx.x;
  if (i < n) out[i] = v;
}

// ---- dense(32->4096) logits: one thread per (b,o); full-device ----
__global__ void logits_k(const float* __restrict__ gap, const void* __restrict__ wd,
                         const void* __restrict__ bd, float* __restrict__ lg,
                         const int* __restrict__ dflag) {
  int i = blockIdx.x * 256 + threadIdx.x;      // 65536 = 16 b x 4096 o
  int b = i >> 12, o = i & 4095;
  int fl = *dflag;
  float s = ldf(bd, o, fl);
  const float scl = 1.0f / 4096.0f;
#pragma unroll
  for (int f = 0; f < 32; f++)
    s += gap[b * 32 + f] * scl * ldf(wd, f * 4096 + o, fl);
  lg[i] = s;
}

// ---- per-batch softmax over 4096 logits ----
__global__ void softmax_k(const float* __restrict__ lg, float* __restrict__ out) {
  int b = blockIdx.x, tid = threadIdx.x;
  __shared__ float red[256];
  float v[16];
  float lmax = -1e30f;
#pragma unroll
  for (int i = 0; i < 16; i++) {
    v[i] = lg[b * 4096 + i * 256 + tid];
    lmax = fmaxf(lmax, v[i]);
  }
  red[tid] = lmax; __syncthreads();
  for (int st = 128; st > 0; st >>= 1) { if (tid < st) red[tid] = fmaxf(red[tid], red[tid + st]); __syncthreads(); }
  float M = red[0]; __syncthreads();
  float ls = 0.f;
#pragma unroll
  for (int i = 0; i < 16; i++) { v[i] = expf(v[i] - M); ls += v[i]; }
  red[tid] = ls; __syncthreads();
  for (int st = 128; st > 0; st >>= 1) { if (tid < st) red[tid] += red[tid + st]; __syncthreads(); }
  float inv = 1.0f / red[0];
#pragma unroll
  for (int i = 0; i < 16; i++) out[b * 4096 + i * 256 + tid] = v[i] * inv;
}

extern "C" void kernel_launch(void* const* d_in, const int* in_sizes, int n_in,
                              void* d_out, int out_size, void* d_ws, size_t ws_size,
                              hipStream_t stream)
{
  const void* x   = d_in[0];
  const void* k1  = d_in[1];
  const void* u1  = d_in[2];
  const void* b1  = d_in[3];
  const void* g1  = d_in[4];
  const void* be1 = d_in[5];
  const void* m1  = d_in[6];
  const void* v1  = d_in[7];
  const void* k2  = d_in[8];
  const void* u2  = d_in[9];
  const void* b2  = d_in[10];
  const void* g2  = d_in[11];
  const void* be2 = d_in[12];
  const void* m2  = d_in[13];
  const void* v2  = d_in[14];
  const void* k3  = d_in[15];
  const void* u3  = d_in[16];
  const void* b3  = d_in[17];
  const void* wd  = d_in[18];
  const void* bd  = d_in[19];
  float* out = (float*)d_out;   // reference output dtype is float32

  char* ws = (char*)d_ws;
  size_t off = 0;
  auto alloc = [&](size_t bytes) -> char* {
    char* p = ws + off; off = (off + bytes + 255) & ~(size_t)255; return p;
  };
  // activation u16 buffers carry 2 planes (hi, lo); p1/p2 also 2 parities
  float* c1  = (float*)alloc(2097152 * 4);
  float* c2  = (float*)alloc(524288 * 4);
  float* c3  = (float*)alloc(131072 * 4);
  u16*   h1a = (u16*)alloc(2097152 * 2 * 2);
  u16*   h2a = (u16*)alloc(524288 * 2 * 2);
  u16*   h3a = (u16*)alloc(131072 * 2 * 2);
  float* gap = (float*)alloc(512 * 4);
  int*   dflag = (int*)alloc(64);
  u16*   zp  = (u16*)alloc(2048);        // zero page for OOB DMA lanes
  size_t zero_bytes = off;               // everything above starts at 0
  u16* h1b = (u16*)alloc(2097152 * 2 * 2);
  u16* h2b = (u16*)alloc(524288 * 2 * 2);
  u16* h3b = (u16*)alloc(131072 * 2 * 2);
  u16* p1  = (u16*)alloc(524288 * 2 * 2 * 2);   // 2 parities x 2 planes
  u16* p2  = (u16*)alloc(131072 * 2 * 2 * 2);
  u16* xc  = (u16*)alloc(1048576 * 2 * 2);
  float* lgbuf = (float*)alloc(65536 * 4);
  u16* W1x = (u16*)alloc(4096 * 2);
  u16* W1u = (u16*)alloc(102400 * 2);
  u16* W2k = (u16*)alloc(102400 * 2);
  u16* W2u = (u16*)alloc(102400 * 2);
  u16* W3k = (u16*)alloc(36864 * 2);
  u16* W3u = (u16*)alloc(36864 * 2);

  if (ws_size < off) {
    fillv<<<dim3((out_size + 255) / 256), 256, 0, stream>>>(out, out_size, 0.5f);
    return;
  }

  int nz = (int)(zero_bytes / 16);
  zero_ws<<<dim3((nz + 255) / 256), 256, 0, stream>>>((int4*)ws, nz);
  detect_dtype<<<1, 256, 0, stream>>>(x, dflag);
  canon_x<<<4096, 256, 0, stream>>>(x, xc, dflag, 1048576);
  repack_x<<<2, 256, 0, stream>>>(k1, W1x, dflag);
  repack_w<<<50, 256, 0, stream>>>(u1, W1u, 25, dflag);
  repack_w<<<50, 256, 0, stream>>>(k2, W2k, 25, dflag);
  repack_w<<<50, 256, 0, stream>>>(u2, W2u, 25, dflag);
  repack_w<<<18, 256, 0, stream>>>(k3, W3k, 9, dflag);
  repack_w<<<18, 256, 0, stream>>>(u3, W3u, 9, dflag);

  // dyn LDS = max over roles: MODE1 4 x 9*512 elems = 36864 B (+sgap pad)
  const size_t dyn = 37120;
  for (int t = 0; t < 18; ++t) {
    fused_step<<<832, 256, dyn, stream>>>(t, xc, zp,
        W1x, W1u, h1a, h1b, c1, b1, g1, be1, m1, v1, p1,
        W2k, W2u, h2a, h2b, c2, b2, g2, be2, m2, v2, p2,
        W3k, W3u, h3a, h3b, c3, b3, gap, dflag);
  }
  logits_k<<<256, 256, 0, stream>>>(gap, wd, bd, lgbuf, dflag);
  softmax_k<<<16, 256, 0, stream>>>(lgbuf, out);
}

// Round 15
// 1197.709 us; speedup vs baseline: 2.7959x; 2.7959x over previous
//
#include <hip/hip_runtime.h>

typedef unsigned short u16;
typedef unsigned int u32;
typedef __attribute__((ext_vector_type(8))) short bf16x8;
typedef __attribute__((ext_vector_type(4))) float f32x4;

__device__ __forceinline__ float b2f(u16 h) {
  union { float f; unsigned u; } v; v.u = ((unsigned)h) << 16; return v.f;
}
__device__ __forceinline__ u16 f2b(float f) {
  union { float f; unsigned u; } v; v.f = f;
  unsigned r = v.u + 0x7fffu + ((v.u >> 16) & 1u);
  return (u16)(r >> 16);
}
__device__ __forceinline__ float hsig(float z) {
  return fminf(fmaxf(z * 0.16666667f + 0.5f, 0.f), 1.f);
}
__device__ __forceinline__ float ldf(const void* p, int i, int flag) {
  return flag ? b2f(((const u16*)p)[i]) : ((const float*)p)[i];
}
// 16B-per-lane DMA: global (per-lane addr) -> LDS (wave-uniform base + lane*16)
__device__ __forceinline__ void glds16(const void* g, void* l) {
  __builtin_amdgcn_global_load_lds(
      (const __attribute__((address_space(1))) void*)g,
      (__attribute__((address_space(3))) void*)(u32)(size_t)l, 16, 0, 0);
}

__global__ void detect_dtype(const void* x, int* dflag) {
  __shared__ int cnt;
  if (threadIdx.x == 0) cnt = 0;
  __syncthreads();
  const u32* w = (const u32*)x;
  int c = 0;
  for (int i = threadIdx.x; i < 512; i += 256) {
    u32 e = (w[i] >> 7) & 0xFFu;
    if (e >= 100 && e < 130) c++;
  }
  atomicAdd(&cnt, c);
  __syncthreads();
  if (threadIdx.x == 0) *dflag = (cnt >= 256) ? 1 : 0;
}

__global__ void canon_x(const void* src, u16* dst, const int* dflag, int n) {
  int i = blockIdx.x * 256 + threadIdx.x;
  if (i >= n) return;
  int fl = *dflag;
  float v = ldf(src, i, fl);
  u16 hi = f2b(v);
  dst[i] = hi;
  dst[i + n] = f2b(v - b2f(hi));
}

// ---------------------------------------------------------------------------
// ConvLSTM step body. Implicit-GEMM MFMA 16x16x32 bf16; hi/lo bf16 pairs,
// single-pass (hi & lo co-staged; weights loaded once per tap, 2x MFMA).
// Staging of 32-ch tensors is global_load_lds DMA (16B/lane) into the
// XOR-swizzled LDS layout; OOB halo lanes read a zeroed global page.
// ROUND-15 FIX: __launch_bounds__(256,3) — round 14's (256,4) squeezed the
// unified VGPR/AGPR file to 64 arch VGPRs -> scratch spills (313 MB writes).
// ---------------------------------------------------------------------------
template<int KS, int MODE, int H, int W, int MROWS>
__device__ __forceinline__
void step_body(int bxi, int b, char* dsm, const u16* __restrict__ zp,
               const u16* __restrict__ src, int aBStride, size_t sPL,
               const u16* __restrict__ wA, const u16* __restrict__ wU,
               const u16* __restrict__ hin, size_t hPL, u16* __restrict__ hout,
               float* __restrict__ cbuf, const void* __restrict__ bias,
               const void* __restrict__ bng, const void* __restrict__ bnb,
               const void* __restrict__ bnm, const void* __restrict__ bnv,
               u16* __restrict__ pooled, size_t pPL, float* __restrict__ gap,
               const int* __restrict__ dflag)
{
  constexpr int PAD = KS / 2;
  constexpr int TW = 8 + 2 * PAD;
  constexpr int TH = MROWS + 2 * PAD;
  constexpr int KK = KS * KS;
  constexpr int KT = (MODE == 0) ? (KK + 1) : (2 * KK);
  constexpr int MT = MROWS / 4;
  constexpr int NPX = TH * TW;
  constexpr int CALLS = (NPX * 32 + 511) / 512;  // 1KB DMA calls per buffer
  constexpr int BUFP = CALLS * 512;              // padded elems per buffer
  constexpr int ASZ0 = (NPX + 15) & ~15;

  u16* sH0 = (u16*)dsm;
  u16* sH1 = sH0 + BUFP;
  u16* sA0 = sH1 + BUFP;
  u16* sA1 = sA0 + ((MODE == 0) ? ASZ0 : BUFP);
  float* sgap = (float*)(sA1 + ((MODE == 0) ? ASZ0 : BUFP));

  const int tid = threadIdx.x;
  constexpr int TXT = W / 8;
  const int bx0 = (bxi % TXT) * 8;
  const int gy0 = (bxi / TXT) * MROWS;

  const int w = tid >> 6, lane = tid & 63;
  const int j = w & 1, R0 = (w >> 1) * (MROWS / 2);
  const int q = lane >> 4, col = lane & 15;
  const int my = (lane >> 3) & 1, mx = lane & 7;

  if (MODE == 2 && tid < 32) sgap[tid] = 0.f;

  // DMA-stage a 32-ch tensor plane into the swizzled LDS buffer
  auto stageC = [&](const u16* gsrc, u16* dst) {
    for (int k = w; k < CALLS; k += 4) {
      int idx = k * 512 + lane * 8;
      int px = idx >> 5;
      int slot = (idx >> 3) & 3;
      int c = (slot ^ px ^ (px >> 1)) & 3;
      int sy = px / TW, sx = px - sy * TW;
      int gy = gy0 + sy - PAD, gx = bx0 + sx - PAD;
      const u16* g = zp;
      if (px < NPX && gy >= 0 && gy < H && gx >= 0 && gx < W)
        g = gsrc + (((size_t)(b * H + gy) * W + gx) << 5) + c * 8;
      glds16(g, dst + (size_t)k * 512);
    }
  };
  auto stageX = [&](int pl, u16* dst) {   // MODE0 single-channel x (small)
    const u16* asrc = src + (size_t)pl * sPL;
    for (int i = tid; i < NPX; i += 256) {
      int sy = i / TW, sx = i - sy * TW;
      int gy = gy0 + sy - PAD, gx = bx0 + sx - PAD;
      u16 v = 0;
      if (gy >= 0 && gy < H && gx >= 0 && gx < W)
        v = asrc[(size_t)b * aBStride + gy * W + gx];
      dst[i] = v;
    }
  };

  const int wfoff = lane * 8;
  auto loadW = [&](int kt, bf16x8* dst) {
    const u16* wsrc;
    if (MODE == 0) wsrc = (kt == 0) ? wA : (wU + (kt - 1) * 4096);
    else           wsrc = (kt < KK) ? (wA + kt * 4096) : (wU + (kt - KK) * 4096);
#pragma unroll
    for (int g = 0; g < 4; g++)
      dst[g] = *(const bf16x8*)(wsrc + ((j + 2 * g) * 64) * 8 + wfoff);
  };

  f32x4 acc[MT][4] = {};
  int pxb[MT];
#pragma unroll
  for (int mt = 0; mt < MT; mt++)
    pxb[mt] = (R0 + 2 * mt + my) * TW + mx;

  stageC(hin, sH0);
  stageC(hin + hPL, sH1);
  if (MODE == 0) { stageX(0, sA0); stageX(1, sA1); }
  else           { stageC(src, sA0); stageC(src + sPL, sA1); }
  __syncthreads();

  bf16x8 bw[4];
  loadW(0, bw);
#pragma unroll 2
  for (int kt = 0; kt < KT; ++kt) {
    bf16x8 nxt[4];
    if (kt + 1 < KT) loadW(kt + 1, nxt);
    bf16x8 ah[MT], al[MT];
    if (MODE == 0 && kt == 0) {
#pragma unroll
      for (int mt = 0; mt < MT; mt++) {
        union { bf16x8 v; u16 e[8]; } uh, ul;
#pragma unroll
        for (int jj = 0; jj < 8; jj++) {
          int k = q * 8 + jj;
          u16 vh = 0, vl = 0;
          if (k < KK) {
            int kh = k / KS, kw = k - kh * KS;
            int o = (R0 + 2 * mt + my + kh) * TW + (mx + kw);
            vh = sA0[o]; vl = sA1[o];
          }
          uh.e[jj] = vh; ul.e[jj] = vl;
        }
        ah[mt] = uh.v; al[mt] = ul.v;
      }
    } else {
      int tap; const u16 *s0, *s1;
      if (MODE == 0)    { tap = kt - 1;  s0 = sH0; s1 = sH1; }
      else if (kt < KK) { tap = kt;      s0 = sA0; s1 = sA1; }
      else              { tap = kt - KK; s0 = sH0; s1 = sH1; }
      const int koff = (tap / KS) * TW + (tap - (tap / KS) * KS);
#pragma unroll
      for (int mt = 0; mt < MT; mt++) {
        const int px = pxb[mt] + koff;
        const int ad = (px << 5) + (((q ^ px ^ (px >> 1)) & 3) << 3);
        ah[mt] = *(const bf16x8*)(s0 + ad);
        al[mt] = *(const bf16x8*)(s1 + ad);
      }
    }
#pragma unroll
    for (int mt = 0; mt < MT; mt++)
#pragma unroll
      for (int g = 0; g < 4; g++)
        acc[mt][g] = __builtin_amdgcn_mfma_f32_16x16x32_bf16(ah[mt], bw[g], acc[mt][g], 0, 0, 0);
#pragma unroll
    for (int mt = 0; mt < MT; mt++)
#pragma unroll
      for (int g = 0; g < 4; g++)
        acc[mt][g] = __builtin_amdgcn_mfma_f32_16x16x32_bf16(al[mt], bw[g], acc[mt][g], 0, 0, 0);
#pragma unroll
    for (int g = 0; g < 4; g++) bw[g] = nxt[g];
  }

  // ---- epilogue: gates, state update, BN+pool / GAP ----
  const int fl = *dflag;
  const int f = j * 16 + col;
  const float bi  = ldf(bias, f, fl);
  const float bff = ldf(bias, 32 + f, fl);
  const float bg  = ldf(bias, 64 + f, fl);
  const float bo  = ldf(bias, 96 + f, fl);
  float sc = 0.f, sh = 0.f;
  if (MODE < 2) {
    sc = ldf(bng, f, fl) * rsqrtf(ldf(bnv, f, fl) + 1e-3f);
    sh = ldf(bnb, f, fl) - ldf(bnm, f, fl) * sc;
  }
  const int oy = q >> 1;
  const int ox = (q & 1) * 4;
  float gsum = 0.f;
#pragma unroll
  for (int mt = 0; mt < MT; mt++) {
    const int y = gy0 + R0 + 2 * mt + oy;
    const size_t base = (((size_t)(b * H + y) * W + (bx0 + ox)) << 5) + f;
    float bnp[4];
#pragma unroll
    for (int r = 0; r < 4; r++) {
      float zi = acc[mt][0][r] + bi;
      float zf = acc[mt][1][r] + bff;
      float zg = acc[mt][2][r] + bg;
      float zo = acc[mt][3][r] + bo;
      float ig = hsig(zi), fg = hsig(zf), og = hsig(zo);
      float gg = fmaxf(zg, 0.f);
      size_t idx = base + ((size_t)r << 5);
      float cold = cbuf[idx];
      float cn = fg * cold + ig * gg;
      cbuf[idx] = cn;
      float hn = og * fmaxf(cn, 0.f);
      u16 hhi = f2b(hn);
      hout[idx] = hhi;
      hout[idx + hPL] = f2b(hn - b2f(hhi));
      if (MODE < 2) bnp[r] = hn * sc + sh; else gsum += hn;
    }
    if (MODE < 2) {
      float p0 = fmaxf(bnp[0], bnp[1]);
      float p1 = fmaxf(bnp[2], bnp[3]);
      p0 = fmaxf(p0, __shfl_xor(p0, 32));
      p1 = fmaxf(p1, __shfl_xor(p1, 32));
      if (q < 2) {
        const int py = (gy0 + R0 + 2 * mt) >> 1;
        const int px = (bx0 >> 1) + (q & 1) * 2;
        size_t pb = (((size_t)(b * (H / 2) + py) * (W / 2) + px) << 5) + f;
        u16 phi = f2b(p0);
        pooled[pb] = phi;
        pooled[pb + pPL] = f2b(p0 - b2f(phi));
        u16 qhi = f2b(p1);
        pooled[pb + 32] = qhi;
        pooled[pb + 32 + pPL] = f2b(p1 - b2f(qhi));
      }
    }
  }
  if (MODE == 2) {
    atomicAdd(&sgap[f], gsum);
    __syncthreads();
    if (tid < 32) atomicAdd(&gap[b * 32 + tid], sgap[tid]);
  }
}

// ---------------------------------------------------------------------------
// Skewed fused dispatch, role-interleaved: 832 = 26 x 32 groups; per group:
// 16 L1(t) + 8 L2(t-1, 8-row) + 2 L3(t-2, 8-row). p1/p2 parity-buffered.
// launch_bounds (256,3): VGPR ~84 + 64 AGPR fits 3 waves/SIMD, no spill.
// ---------------------------------------------------------------------------
__global__ __launch_bounds__(256, 3)
void fused_step(int t, const u16* __restrict__ xc, const u16* __restrict__ zp,
                const u16* __restrict__ W1x, const u16* __restrict__ W1u,
                u16* h1a, u16* h1b, float* c1, const void* b1, const void* g1,
                const void* be1, const void* m1, const void* v1, u16* p1,
                const u16* __restrict__ W2k, const u16* __restrict__ W2u,
                u16* h2a, u16* h2b, float* c2, const void* b2, const void* g2,
                const void* be2, const void* m2, const void* v2, u16* p2,
                const u16* __restrict__ W3k, const u16* __restrict__ W3u,
                u16* h3a, u16* h3b, float* c3, const void* b3,
                float* gap, const int* dflag)
{
  extern __shared__ char dsm[];
  const int grp = blockIdx.x / 26;
  const int r   = blockIdx.x % 26;
  if (r < 16) {
    if (t > 15) return;
    const int idx = grp * 16 + r;            // 0..511
    const u16* h1i = (t & 1) ? h1b : h1a; u16* h1o = (t & 1) ? h1a : h1b;
    step_body<5, 0, 64, 64, 16>(idx & 31, idx >> 5, dsm, zp,
        xc + (size_t)t * 4096, 65536, 1048576, W1x, W1u, h1i, 2097152, h1o, c1,
        b1, g1, be1, m1, v1, p1 + (size_t)(t & 1) * 1048576, 524288, nullptr, dflag);
  } else if (r < 24) {
    const int tt = t - 1; if (tt < 0 || tt > 15) return;
    const int idx = grp * 8 + (r - 16);      // 0..255 (16 tiles x 16 b)
    const u16* h2i = (tt & 1) ? h2b : h2a; u16* h2o = (tt & 1) ? h2a : h2b;
    step_body<5, 1, 32, 32, 8>(idx & 15, idx >> 4, dsm, zp,
        p1 + (size_t)(tt & 1) * 1048576, 32768, 524288, W2k, W2u, h2i, 524288, h2o, c2,
        b2, g2, be2, m2, v2, p2 + (size_t)(tt & 1) * 262144, 131072, nullptr, dflag);
  } else {
    const int tt = t - 2; if (tt < 0 || tt > 15) return;
    const int idx = grp * 2 + (r - 24);      // 0..63 (4 tiles x 16 b)
    const u16* h3i = (tt & 1) ? h3b : h3a; u16* h3o = (tt & 1) ? h3a : h3b;
    step_body<3, 2, 16, 16, 8>(idx & 3, idx >> 2, dsm, zp,
        p2 + (size_t)(tt & 1) * 262144, 8192, 131072, W3k, W3u, h3i, 131072, h3o, c3,
        b3, nullptr, nullptr, nullptr, nullptr, nullptr, 0, gap, dflag);
  }
}

__global__ void repack_w(const void* __restrict__ src, u16* __restrict__ dst,
                         int taps, const int* __restrict__ dflag) {
  int i = blockIdx.x * 256 + threadIdx.x;
  if (i >= taps * 512) return;
  int fl = *dflag;
  int l = i & 63, nt = (i >> 6) & 7, tap = i >> 9;
  int q = l >> 4, col = l & 15;
  u16 tmp[8];
#pragma unroll
  for (int j = 0; j < 8; j++)
    tmp[j] = f2b(ldf(src, (tap * 32 + q * 8 + j) * 128 + nt * 16 + col, fl));
#pragma unroll
  for (int j = 0; j < 8; j++) dst[i * 8 + j] = tmp[j];
}
__global__ void repack_x(const void* __restrict__ src, u16* __restrict__ dst,
                         const int* __restrict__ dflag) {
  int i = blockIdx.x * 256 + threadIdx.x;
  if (i >= 512) return;
  int fl = *dflag;
  int l = i & 63, nt = (i >> 6) & 7;
  int q = l >> 4, col = l & 15;
#pragma unroll
  for (int j = 0; j < 8; j++) {
    int k = q * 8 + j;
    dst[i * 8 + j] = (k < 25) ? f2b(ldf(src, k * 128 + nt * 16 + col, fl)) : (u16)0;
  }
}

__global__ void zero_ws(int4* p, int n) {
  int i = blockIdx.x * 256 + threadIdx.x;
  if (i < n) { int4 z; z.x = z.y = z.z = z.w = 0; p[i] = z; }
}
__global__ void fillv(float* out, int n, float v) {
  int i = blockIdx.x * 256 + threadIdx.x;
  if (i < n) out[i] = v;
}

// ---- dense(32->4096) logits: one thread per (b,o); full-device ----
__global__ void logits_k(const float* __restrict__ gap, const void* __restrict__ wd,
                         const void* __restrict__ bd, float* __restrict__ lg,
                         const int* __restrict__ dflag) {
  int i = blockIdx.x * 256 + threadIdx.x;      // 65536 = 16 b x 4096 o
  int b = i >> 12, o = i & 4095;
  int fl = *dflag;
  float s = ldf(bd, o, fl);
  const float scl = 1.0f / 4096.0f;
#pragma unroll
  for (int f = 0; f < 32; f++)
    s += gap[b * 32 + f] * scl * ldf(wd, f * 4096 + o, fl);
  lg[i] = s;
}

// ---- per-batch softmax over 4096 logits ----
__global__ void softmax_k(const float* __restrict__ lg, float* __restrict__ out) {
  int b = blockIdx.x, tid = threadIdx.x;
  __shared__ float red[256];
  float v[16];
  float lmax = -1e30f;
#pragma unroll
  for (int i = 0; i < 16; i++) {
    v[i] = lg[b * 4096 + i * 256 + tid];
    lmax = fmaxf(lmax, v[i]);
  }
  red[tid] = lmax; __syncthreads();
  for (int st = 128; st > 0; st >>= 1) { if (tid < st) red[tid] = fmaxf(red[tid], red[tid + st]); __syncthreads(); }
  float M = red[0]; __syncthreads();
  float ls = 0.f;
#pragma unroll
  for (int i = 0; i < 16; i++) { v[i] = expf(v[i] - M); ls += v[i]; }
  red[tid] = ls; __syncthreads();
  for (int st = 128; st > 0; st >>= 1) { if (tid < st) red[tid] += red[tid + st]; __syncthreads(); }
  float inv = 1.0f / red[0];
#pragma unroll
  for (int i = 0; i < 16; i++) out[b * 4096 + i * 256 + tid] = v[i] * inv;
}

extern "C" void kernel_launch(void* const* d_in, const int* in_sizes, int n_in,
                              void* d_out, int out_size, void* d_ws, size_t ws_size,
                              hipStream_t stream)
{
  const void* x   = d_in[0];
  const void* k1  = d_in[1];
  const void* u1  = d_in[2];
  const void* b1  = d_in[3];
  const void* g1  = d_in[4];
  const void* be1 = d_in[5];
  const void* m1  = d_in[6];
  const void* v1  = d_in[7];
  const void* k2  = d_in[8];
  const void* u2  = d_in[9];
  const void* b2  = d_in[10];
  const void* g2  = d_in[11];
  const void* be2 = d_in[12];
  const void* m2  = d_in[13];
  const void* v2  = d_in[14];
  const void* k3  = d_in[15];
  const void* u3  = d_in[16];
  const void* b3  = d_in[17];
  const void* wd  = d_in[18];
  const void* bd  = d_in[19];
  float* out = (float*)d_out;   // reference output dtype is float32

  char* ws = (char*)d_ws;
  size_t off = 0;
  auto alloc = [&](size_t bytes) -> char* {
    char* p = ws + off; off = (off + bytes + 255) & ~(size_t)255; return p;
  };
  // activation u16 buffers carry 2 planes (hi, lo); p1/p2 also 2 parities
  float* c1  = (float*)alloc(2097152 * 4);
  float* c2  = (float*)alloc(524288 * 4);
  float* c3  = (float*)alloc(131072 * 4);
  u16*   h1a = (u16*)alloc(2097152 * 2 * 2);
  u16*   h2a = (u16*)alloc(524288 * 2 * 2);
  u16*   h3a = (u16*)alloc(131072 * 2 * 2);
  float* gap = (float*)alloc(512 * 4);
  int*   dflag = (int*)alloc(64);
  u16*   zp  = (u16*)alloc(2048);        // zero page for OOB DMA lanes
  size_t zero_bytes = off;               // everything above starts at 0
  u16* h1b = (u16*)alloc(2097152 * 2 * 2);
  u16* h2b = (u16*)alloc(524288 * 2 * 2);
  u16* h3b = (u16*)alloc(131072 * 2 * 2);
  u16* p1  = (u16*)alloc(524288 * 2 * 2 * 2);   // 2 parities x 2 planes
  u16* p2  = (u16*)alloc(131072 * 2 * 2 * 2);
  u16* xc  = (u16*)alloc(1048576 * 2 * 2);
  float* lgbuf = (float*)alloc(65536 * 4);
  u16* W1x = (u16*)alloc(4096 * 2);
  u16* W1u = (u16*)alloc(102400 * 2);
  u16* W2k = (u16*)alloc(102400 * 2);
  u16* W2u = (u16*)alloc(102400 * 2);
  u16* W3k = (u16*)alloc(36864 * 2);
  u16* W3u = (u16*)alloc(36864 * 2);

  if (ws_size < off) {
    fillv<<<dim3((out_size + 255) / 256), 256, 0, stream>>>(out, out_size, 0.5f);
    return;
  }

  int nz = (int)(zero_bytes / 16);
  zero_ws<<<dim3((nz + 255) / 256), 256, 0, stream>>>((int4*)ws, nz);
  detect_dtype<<<1, 256, 0, stream>>>(x, dflag);
  canon_x<<<4096, 256, 0, stream>>>(x, xc, dflag, 1048576);
  repack_x<<<2, 256, 0, stream>>>(k1, W1x, dflag);
  repack_w<<<50, 256, 0, stream>>>(u1, W1u, 25, dflag);
  repack_w<<<50, 256, 0, stream>>>(k2, W2k, 25, dflag);
  repack_w<<<50, 256, 0, stream>>>(u2, W2u, 25, dflag);
  repack_w<<<18, 256, 0, stream>>>(k3, W3k, 9, dflag);
  repack_w<<<18, 256, 0, stream>>>(u3, W3u, 9, dflag);

  // dyn LDS = max over roles: MODE1 4 x 9*512 elems = 36864 B (+sgap pad)
  const size_t dyn = 37120;
  for (int t = 0; t < 18; ++t) {
    fused_step<<<832, 256, dyn, stream>>>(t, xc, zp,
        W1x, W1u, h1a, h1b, c1, b1, g1, be1, m1, v1, p1,
        W2k, W2u, h2a, h2b, c2, b2, g2, be2, m2, v2, p2,
        W3k, W3u, h3a, h3b, c3, b3, gap, dflag);
  }
  logits_k<<<256, 256, 0, stream>>>(gap, wd, bd, lgbuf, dflag);
  softmax_k<<<16, 256, 0, stream>>>(lgbuf, out);
}

// Round 16
// 1010.835 us; speedup vs baseline: 3.3127x; 1.1849x over previous
//
#include <hip/hip_runtime.h>

typedef unsigned short u16;
typedef unsigned int u32;
typedef __attribute__((ext_vector_type(8))) short bf16x8;
typedef __attribute__((ext_vector_type(4))) float f32x4;

__device__ __forceinline__ float b2f(u16 h) {
  union { float f; unsigned u; } v; v.u = ((unsigned)h) << 16; return v.f;
}
__device__ __forceinline__ u16 f2b(float f) {
  union { float f; unsigned u; } v; v.f = f;
  unsigned r = v.u + 0x7fffu + ((v.u >> 16) & 1u);
  return (u16)(r >> 16);
}
__device__ __forceinline__ float hsig(float z) {
  return fminf(fmaxf(z * 0.16666667f + 0.5f, 0.f), 1.f);
}
__device__ __forceinline__ float ldf(const void* p, int i, int flag) {
  return flag ? b2f(((const u16*)p)[i]) : ((const float*)p)[i];
}
// 16B-per-lane DMA: global (per-lane addr) -> LDS (wave-uniform base + lane*16)
__device__ __forceinline__ void glds16(const void* g, void* l) {
  __builtin_amdgcn_global_load_lds(
      (const __attribute__((address_space(1))) void*)g,
      (__attribute__((address_space(3))) void*)(u32)(size_t)l, 16, 0, 0);
}

__global__ void detect_dtype(const void* x, int* dflag) {
  __shared__ int cnt;
  if (threadIdx.x == 0) cnt = 0;
  __syncthreads();
  const u32* w = (const u32*)x;
  int c = 0;
  for (int i = threadIdx.x; i < 512; i += 256) {
    u32 e = (w[i] >> 7) & 0xFFu;
    if (e >= 100 && e < 130) c++;
  }
  atomicAdd(&cnt, c);
  __syncthreads();
  if (threadIdx.x == 0) *dflag = (cnt >= 256) ? 1 : 0;
}

__global__ void canon_x(const void* src, u16* dst, const int* dflag, int n) {
  int i = blockIdx.x * 256 + threadIdx.x;
  if (i >= n) return;
  int fl = *dflag;
  float v = ldf(src, i, fl);
  u16 hi = f2b(v);
  dst[i] = hi;
  dst[i + n] = f2b(v - b2f(hi));
}

// ---------------------------------------------------------------------------
// ConvLSTM step body. Implicit-GEMM MFMA 16x16x32 bf16; hi/lo bf16 pairs,
// single-pass (hi & lo co-staged; weights loaded once per tap, 2x MFMA).
// ROUND-16: register-pressure surgery so (256,3) fits WITHOUT scratch spill
// (r13-r15 spilled ~22 MB/dispatch: VGPR forced 112->84, WRITE 23->45 MB).
//  - MODE0 kt=0 x-conv peeled out of the main loop (per-mt short live ranges)
//  - hi/lo A-fragments loaded in two phases reusing the same registers
//  - weight prefetch depth 1; #pragma unroll 1 on the K-loop
// Math is bit-identical to round 15 (same per-accumulator MFMA order).
// ---------------------------------------------------------------------------
template<int KS, int MODE, int H, int W, int MROWS>
__device__ __forceinline__
void step_body(int bxi, int b, char* dsm, const u16* __restrict__ zp,
               const u16* __restrict__ src, int aBStride, size_t sPL,
               const u16* __restrict__ wA, const u16* __restrict__ wU,
               const u16* __restrict__ hin, size_t hPL, u16* __restrict__ hout,
               float* __restrict__ cbuf, const void* __restrict__ bias,
               const void* __restrict__ bng, const void* __restrict__ bnb,
               const void* __restrict__ bnm, const void* __restrict__ bnv,
               u16* __restrict__ pooled, size_t pPL, float* __restrict__ gap,
               const int* __restrict__ dflag)
{
  constexpr int PAD = KS / 2;
  constexpr int TW = 8 + 2 * PAD;
  constexpr int TH = MROWS + 2 * PAD;
  constexpr int KK = KS * KS;
  constexpr int KT = (MODE == 0) ? (KK + 1) : (2 * KK);
  constexpr int MT = MROWS / 4;
  constexpr int NPX = TH * TW;
  constexpr int CALLS = (NPX * 32 + 511) / 512;  // 1KB DMA calls per buffer
  constexpr int BUFP = CALLS * 512;              // padded elems per buffer
  constexpr int ASZ0 = (NPX + 15) & ~15;

  u16* sH0 = (u16*)dsm;
  u16* sH1 = sH0 + BUFP;
  u16* sA0 = sH1 + BUFP;
  u16* sA1 = sA0 + ((MODE == 0) ? ASZ0 : BUFP);
  float* sgap = (float*)(sA1 + ((MODE == 0) ? ASZ0 : BUFP));

  const int tid = threadIdx.x;
  constexpr int TXT = W / 8;
  const int bx0 = (bxi % TXT) * 8;
  const int gy0 = (bxi / TXT) * MROWS;

  const int w = tid >> 6, lane = tid & 63;
  const int j = w & 1, R0 = (w >> 1) * (MROWS / 2);
  const int q = lane >> 4, col = lane & 15;
  const int my = (lane >> 3) & 1, mx = lane & 7;

  if (MODE == 2 && tid < 32) sgap[tid] = 0.f;

  // DMA-stage a 32-ch tensor plane into the swizzled LDS buffer
  auto stageC = [&](const u16* gsrc, u16* dst) {
    for (int k = w; k < CALLS; k += 4) {
      int idx = k * 512 + lane * 8;
      int px = idx >> 5;
      int slot = (idx >> 3) & 3;
      int c = (slot ^ px ^ (px >> 1)) & 3;
      int sy = px / TW, sx = px - sy * TW;
      int gy = gy0 + sy - PAD, gx = bx0 + sx - PAD;
      const u16* g = zp;
      if (px < NPX && gy >= 0 && gy < H && gx >= 0 && gx < W)
        g = gsrc + (((size_t)(b * H + gy) * W + gx) << 5) + c * 8;
      glds16(g, dst + (size_t)k * 512);
    }
  };
  auto stageX = [&](int pl, u16* dst) {   // MODE0 single-channel x (small)
    const u16* asrc = src + (size_t)pl * sPL;
    for (int i = tid; i < NPX; i += 256) {
      int sy = i / TW, sx = i - sy * TW;
      int gy = gy0 + sy - PAD, gx = bx0 + sx - PAD;
      u16 v = 0;
      if (gy >= 0 && gy < H && gx >= 0 && gx < W)
        v = asrc[(size_t)b * aBStride + gy * W + gx];
      dst[i] = v;
    }
  };

  const int wfoff = lane * 8;
  auto loadW = [&](int kt, bf16x8* dst) {
    const u16* wsrc;
    if (MODE == 0) wsrc = (kt == 0) ? wA : (wU + (kt - 1) * 4096);
    else           wsrc = (kt < KK) ? (wA + kt * 4096) : (wU + (kt - KK) * 4096);
#pragma unroll
    for (int g = 0; g < 4; g++)
      dst[g] = *(const bf16x8*)(wsrc + ((j + 2 * g) * 64) * 8 + wfoff);
  };

  f32x4 acc[MT][4] = {};
  int pxb[MT];
#pragma unroll
  for (int mt = 0; mt < MT; mt++)
    pxb[mt] = (R0 + 2 * mt + my) * TW + mx;

  stageC(hin, sH0);
  stageC(hin + hPL, sH1);
  if (MODE == 0) { stageX(0, sA0); stageX(1, sA1); }
  else           { stageC(src, sA0); stageC(src + sPL, sA1); }
  __syncthreads();

  bf16x8 bw[4];
  loadW(0, bw);

  int kt0 = 0;
  if (MODE == 0) {
    // ---- peeled kt=0: x-conv as GEMM over taps, per-mt short live ranges
#pragma unroll
    for (int mt = 0; mt < MT; mt++) {
      union { bf16x8 v; u16 e[8]; } uh, ul;
#pragma unroll
      for (int jj = 0; jj < 8; jj++) {
        int k = q * 8 + jj;
        u16 vh = 0, vl = 0;
        if (k < KK) {
          int kh = k / KS, kw = k - kh * KS;
          int o = (R0 + 2 * mt + my + kh) * TW + (mx + kw);
          vh = sA0[o]; vl = sA1[o];
        }
        uh.e[jj] = vh; ul.e[jj] = vl;
      }
#pragma unroll
      for (int g = 0; g < 4; g++)
        acc[mt][g] = __builtin_amdgcn_mfma_f32_16x16x32_bf16(uh.v, bw[g], acc[mt][g], 0, 0, 0);
#pragma unroll
      for (int g = 0; g < 4; g++)
        acc[mt][g] = __builtin_amdgcn_mfma_f32_16x16x32_bf16(ul.v, bw[g], acc[mt][g], 0, 0, 0);
    }
    loadW(1, bw);
    kt0 = 1;
  }

#pragma unroll 1
  for (int kt = kt0; kt < KT; ++kt) {
    int tap; const u16 *s0, *s1;
    if (MODE == 0)    { tap = kt - 1;  s0 = sH0; s1 = sH1; }
    else if (kt < KK) { tap = kt;      s0 = sA0; s1 = sA1; }
    else              { tap = kt - KK; s0 = sH0; s1 = sH1; }
    const int koff = (tap / KS) * TW + (tap - (tap / KS) * KS);
    int ad[MT];
#pragma unroll
    for (int mt = 0; mt < MT; mt++) {
      const int px = pxb[mt] + koff;
      ad[mt] = (px << 5) + (((q ^ px ^ (px >> 1)) & 3) << 3);
    }
    bf16x8 a[MT];
#pragma unroll
    for (int mt = 0; mt < MT; mt++)
      a[mt] = *(const bf16x8*)(s0 + ad[mt]);
    bf16x8 nxt[4];
    if (kt + 1 < KT) loadW(kt + 1, nxt);
#pragma unroll
    for (int mt = 0; mt < MT; mt++)
#pragma unroll
      for (int g = 0; g < 4; g++)
        acc[mt][g] = __builtin_amdgcn_mfma_f32_16x16x32_bf16(a[mt], bw[g], acc[mt][g], 0, 0, 0);
#pragma unroll
    for (int mt = 0; mt < MT; mt++)
      a[mt] = *(const bf16x8*)(s1 + ad[mt]);
#pragma unroll
    for (int mt = 0; mt < MT; mt++)
#pragma unroll
      for (int g = 0; g < 4; g++)
        acc[mt][g] = __builtin_amdgcn_mfma_f32_16x16x32_bf16(a[mt], bw[g], acc[mt][g], 0, 0, 0);
#pragma unroll
    for (int g = 0; g < 4; g++) bw[g] = nxt[g];
  }

  // ---- epilogue: gates, state update, BN+pool / GAP ----
  const int fl = *dflag;
  const int f = j * 16 + col;
  const float bi  = ldf(bias, f, fl);
  const float bff = ldf(bias, 32 + f, fl);
  const float bg  = ldf(bias, 64 + f, fl);
  const float bo  = ldf(bias, 96 + f, fl);
  float sc = 0.f, sh = 0.f;
  if (MODE < 2) {
    sc = ldf(bng, f, fl) * rsqrtf(ldf(bnv, f, fl) + 1e-3f);
    sh = ldf(bnb, f, fl) - ldf(bnm, f, fl) * sc;
  }
  const int oy = q >> 1;
  const int ox = (q & 1) * 4;
  float gsum = 0.f;
#pragma unroll
  for (int mt = 0; mt < MT; mt++) {
    const int y = gy0 + R0 + 2 * mt + oy;
    const size_t base = (((size_t)(b * H + y) * W + (bx0 + ox)) << 5) + f;
    float bnp[4];
#pragma unroll
    for (int r = 0; r < 4; r++) {
      float zi = acc[mt][0][r] + bi;
      float zf = acc[mt][1][r] + bff;
      float zg = acc[mt][2][r] + bg;
      float zo = acc[mt][3][r] + bo;
      float ig = hsig(zi), fg = hsig(zf), og = hsig(zo);
      float gg = fmaxf(zg, 0.f);
      size_t idx = base + ((size_t)r << 5);
      float cold = cbuf[idx];
      float cn = fg * cold + ig * gg;
      cbuf[idx] = cn;
      float hn = og * fmaxf(cn, 0.f);
      u16 hhi = f2b(hn);
      hout[idx] = hhi;
      hout[idx + hPL] = f2b(hn - b2f(hhi));
      if (MODE < 2) bnp[r] = hn * sc + sh; else gsum += hn;
    }
    if (MODE < 2) {
      float p0 = fmaxf(bnp[0], bnp[1]);
      float p1 = fmaxf(bnp[2], bnp[3]);
      p0 = fmaxf(p0, __shfl_xor(p0, 32));
      p1 = fmaxf(p1, __shfl_xor(p1, 32));
      if (q < 2) {
        const int py = (gy0 + R0 + 2 * mt) >> 1;
        const int px = (bx0 >> 1) + (q & 1) * 2;
        size_t pb = (((size_t)(b * (H / 2) + py) * (W / 2) + px) << 5) + f;
        u16 phi = f2b(p0);
        pooled[pb] = phi;
        pooled[pb + pPL] = f2b(p0 - b2f(phi));
        u16 qhi = f2b(p1);
        pooled[pb + 32] = qhi;
        pooled[pb + 32 + pPL] = f2b(p1 - b2f(qhi));
      }
    }
  }
  if (MODE == 2) {
    atomicAdd(&sgap[f], gsum);
    __syncthreads();
    if (tid < 32) atomicAdd(&gap[b * 32 + tid], sgap[tid]);
  }
}

// ---------------------------------------------------------------------------
// Skewed fused dispatch, role-interleaved: 832 = 26 x 32 groups; per group:
// 16 L1(t) + 8 L2(t-1, 8-row) + 2 L3(t-2, 8-row). p1/p2 parity-buffered.
// ---------------------------------------------------------------------------
__global__ __launch_bounds__(256, 3)
void fused_step(int t, const u16* __restrict__ xc, const u16* __restrict__ zp,
                const u16* __restrict__ W1x, const u16* __restrict__ W1u,
                u16* h1a, u16* h1b, float* c1, const void* b1, const void* g1,
                const void* be1, const void* m1, const void* v1, u16* p1,
                const u16* __restrict__ W2k, const u16* __restrict__ W2u,
                u16* h2a, u16* h2b, float* c2, const void* b2, const void* g2,
                const void* be2, const void* m2, const void* v2, u16* p2,
                const u16* __restrict__ W3k, const u16* __restrict__ W3u,
                u16* h3a, u16* h3b, float* c3, const void* b3,
                float* gap, const int* dflag)
{
  extern __shared__ char dsm[];
  const int grp = blockIdx.x / 26;
  const int r   = blockIdx.x % 26;
  if (r < 16) {
    if (t > 15) return;
    const int idx = grp * 16 + r;            // 0..511
    const u16* h1i = (t & 1) ? h1b : h1a; u16* h1o = (t & 1) ? h1a : h1b;
    step_body<5, 0, 64, 64, 16>(idx & 31, idx >> 5, dsm, zp,
        xc + (size_t)t * 4096, 65536, 1048576, W1x, W1u, h1i, 2097152, h1o, c1,
        b1, g1, be1, m1, v1, p1 + (size_t)(t & 1) * 1048576, 524288, nullptr, dflag);
  } else if (r < 24) {
    const int tt = t - 1; if (tt < 0 || tt > 15) return;
    const int idx = grp * 8 + (r - 16);      // 0..255 (16 tiles x 16 b)
    const u16* h2i = (tt & 1) ? h2b : h2a; u16* h2o = (tt & 1) ? h2a : h2b;
    step_body<5, 1, 32, 32, 8>(idx & 15, idx >> 4, dsm, zp,
        p1 + (size_t)(tt & 1) * 1048576, 32768, 524288, W2k, W2u, h2i, 524288, h2o, c2,
        b2, g2, be2, m2, v2, p2 + (size_t)(tt & 1) * 262144, 131072, nullptr, dflag);
  } else {
    const int tt = t - 2; if (tt < 0 || tt > 15) return;
    const int idx = grp * 2 + (r - 24);      // 0..63 (4 tiles x 16 b)
    const u16* h3i = (tt & 1) ? h3b : h3a; u16* h3o = (tt & 1) ? h3a : h3b;
    step_body<3, 2, 16, 16, 8>(idx & 3, idx >> 2, dsm, zp,
        p2 + (size_t)(tt & 1) * 262144, 8192, 131072, W3k, W3u, h3i, 131072, h3o, c3,
        b3, nullptr, nullptr, nullptr, nullptr, nullptr, 0, gap, dflag);
  }
}

__global__ void repack_w(const void* __restrict__ src, u16* __restrict__ dst,
                         int taps, const int* __restrict__ dflag) {
  int i = blockIdx.x * 256 + threadIdx.x;
  if (i >= taps * 512) return;
  int fl = *dflag;
  int l = i & 63, nt = (i >> 6) & 7, tap = i >> 9;
  int q = l >> 4, col = l & 15;
  u16 tmp[8];
#pragma unroll
  for (int j = 0; j < 8; j++)
    tmp[j] = f2b(ldf(src, (tap * 32 + q * 8 + j) * 128 + nt * 16 + col, fl));
#pragma unroll
  for (int j = 0; j < 8; j++) dst[i * 8 + j] = tmp[j];
}
__global__ void repack_x(const void* __restrict__ src, u16* __restrict__ dst,
                         const int* __restrict__ dflag) {
  int i = blockIdx.x * 256 + threadIdx.x;
  if (i >= 512) return;
  int fl = *dflag;
  int l = i & 63, nt = (i >> 6) & 7;
  int q = l >> 4, col = l & 15;
#pragma unroll
  for (int j = 0; j < 8; j++) {
    int k = q * 8 + j;
    dst[i * 8 + j] = (k < 25) ? f2b(ldf(src, k * 128 + nt * 16 + col, fl)) : (u16)0;
  }
}

__global__ void zero_ws(int4* p, int n) {
  int i = blockIdx.x * 256 + threadIdx.x;
  if (i < n) { int4 z; z.x = z.y = z.z = z.w = 0; p[i] = z; }
}
__global__ void fillv(float* out, int n, float v) {
  int i = blockIdx.x * 256 + threadIdx.x;
  if (i < n) out[i] = v;
}

// ---- dense(32->4096) logits: one thread per (b,o); full-device ----
__global__ void logits_k(const float* __restrict__ gap, const void* __restrict__ wd,
                         const void* __restrict__ bd, float* __restrict__ lg,
                         const int* __restrict__ dflag) {
  int i = blockIdx.x * 256 + threadIdx.x;      // 65536 = 16 b x 4096 o
  int b = i >> 12, o = i & 4095;
  int fl = *dflag;
  float s = ldf(bd, o, fl);
  const float scl = 1.0f / 4096.0f;
#pragma unroll
  for (int f = 0; f < 32; f++)
    s += gap[b * 32 + f] * scl * ldf(wd, f * 4096 + o, fl);
  lg[i] = s;
}

// ---- per-batch softmax over 4096 logits ----
__global__ void softmax_k(const float* __restrict__ lg, float* __restrict__ out) {
  int b = blockIdx.x, tid = threadIdx.x;
  __shared__ float red[256];
  float v[16];
  float lmax = -1e30f;
#pragma unroll
  for (int i = 0; i < 16; i++) {
    v[i] = lg[b * 4096 + i * 256 + tid];
    lmax = fmaxf(lmax, v[i]);
  }
  red[tid] = lmax; __syncthreads();
  for (int st = 128; st > 0; st >>= 1) { if (tid < st) red[tid] = fmaxf(red[tid], red[tid + st]); __syncthreads(); }
  float M = red[0]; __syncthreads();
  float ls = 0.f;
#pragma unroll
  for (int i = 0; i < 16; i++) { v[i] = expf(v[i] - M); ls += v[i]; }
  red[tid] = ls; __syncthreads();
  for (int st = 128; st > 0; st >>= 1) { if (tid < st) red[tid] += red[tid + st]; __syncthreads(); }
  float inv = 1.0f / red[0];
#pragma unroll
  for (int i = 0; i < 16; i++) out[b * 4096 + i * 256 + tid] = v[i] * inv;
}

extern "C" void kernel_launch(void* const* d_in, const int* in_sizes, int n_in,
                              void* d_out, int out_size, void* d_ws, size_t ws_size,
                              hipStream_t stream)
{
  const void* x   = d_in[0];
  const void* k1  = d_in[1];
  const void* u1  = d_in[2];
  const void* b1  = d_in[3];
  const void* g1  = d_in[4];
  const void* be1 = d_in[5];
  const void* m1  = d_in[6];
  const void* v1  = d_in[7];
  const void* k2  = d_in[8];
  const void* u2  = d_in[9];
  const void* b2  = d_in[10];
  const void* g2  = d_in[11];
  const void* be2 = d_in[12];
  const void* m2  = d_in[13];
  const void* v2  = d_in[14];
  const void* k3  = d_in[15];
  const void* u3  = d_in[16];
  const void* b3  = d_in[17];
  const void* wd  = d_in[18];
  const void* bd  = d_in[19];
  float* out = (float*)d_out;   // reference output dtype is float32

  char* ws = (char*)d_ws;
  size_t off = 0;
  auto alloc = [&](size_t bytes) -> char* {
    char* p = ws + off; off = (off + bytes + 255) & ~(size_t)255; return p;
  };
  // activation u16 buffers carry 2 planes (hi, lo); p1/p2 also 2 parities
  float* c1  = (float*)alloc(2097152 * 4);
  float* c2  = (float*)alloc(524288 * 4);
  float* c3  = (float*)alloc(131072 * 4);
  u16*   h1a = (u16*)alloc(2097152 * 2 * 2);
  u16*   h2a = (u16*)alloc(524288 * 2 * 2);
  u16*   h3a = (u16*)alloc(131072 * 2 * 2);
  float* gap = (float*)alloc(512 * 4);
  int*   dflag = (int*)alloc(64);
  u16*   zp  = (u16*)alloc(2048);        // zero page for OOB DMA lanes
  size_t zero_bytes = off;               // everything above starts at 0
  u16* h1b = (u16*)alloc(2097152 * 2 * 2);
  u16* h2b = (u16*)alloc(524288 * 2 * 2);
  u16* h3b = (u16*)alloc(131072 * 2 * 2);
  u16* p1  = (u16*)alloc(524288 * 2 * 2 * 2);   // 2 parities x 2 planes
  u16* p2  = (u16*)alloc(131072 * 2 * 2 * 2);
  u16* xc  = (u16*)alloc(1048576 * 2 * 2);
  float* lgbuf = (float*)alloc(65536 * 4);
  u16* W1x = (u16*)alloc(4096 * 2);
  u16* W1u = (u16*)alloc(102400 * 2);
  u16* W2k = (u16*)alloc(102400 * 2);
  u16* W2u = (u16*)alloc(102400 * 2);
  u16* W3k = (u16*)alloc(36864 * 2);
  u16* W3u = (u16*)alloc(36864 * 2);

  if (ws_size < off) {
    fillv<<<dim3((out_size + 255) / 256), 256, 0, stream>>>(out, out_size, 0.5f);
    return;
  }

  int nz = (int)(zero_bytes / 16);
  zero_ws<<<dim3((nz + 255) / 256), 256, 0, stream>>>((int4*)ws, nz);
  detect_dtype<<<1, 256, 0, stream>>>(x, dflag);
  canon_x<<<4096, 256, 0, stream>>>(x, xc, dflag, 1048576);
  repack_x<<<2, 256, 0, stream>>>(k1, W1x, dflag);
  repack_w<<<50, 256, 0, stream>>>(u1, W1u, 25, dflag);
  repack_w<<<50, 256, 0, stream>>>(k2, W2k, 25, dflag);
  repack_w<<<50, 256, 0, stream>>>(u2, W2u, 25, dflag);
  repack_w<<<18, 256, 0, stream>>>(k3, W3k, 9, dflag);
  repack_w<<<18, 256, 0, stream>>>(u3, W3u, 9, dflag);

  // dyn LDS = max over roles: MODE1 4 x 9*512 elems = 36864 B (+sgap pad)
  const size_t dyn = 37120;
  for (int t = 0; t < 18; ++t) {
    fused_step<<<832, 256, dyn, stream>>>(t, xc, zp,
        W1x, W1u, h1a, h1b, c1, b1, g1, be1, m1, v1, p1,
        W2k, W2u, h2a, h2b, c2, b2, g2, be2, m2, v2, p2,
        W3k, W3u, h3a, h3b, c3, b3, gap, dflag);
  }
  logits_k<<<256, 256, 0, stream>>>(gap, wd, bd, lgbuf, dflag);
  softmax_k<<<16, 256, 0, stream>>>(lgbuf, out);
}